// Round 5
// baseline (69.496 us; speedup 1.0000x reference)
//
#include <hip/hip_runtime.h>

typedef float f4 __attribute__((ext_vector_type(4)));

#define BB 32
#define CC 512
#define LL 4096
#define NB 16
#define EPSF 1e-8f

// ---------------- fused main kernel: barrier-free, ONE read of x ----------
// grid = 32 b x 16 chunks = 512 blocks (2/CU). Wave w owns channels
// c0+8w..c0+8w+7 and processes each row fully in registers:
//   load 16 f4 (lane holds l = 256i + 4*lane + k) -> reg row-sum ->
//   shuffle-reduce -> broadcast g -> FMA in place into 16+16 f4 accums.
// No LDS / no barriers in the hot loop; 8 independent waves/CU keep the
// HBM queue fed. One 4-step LDS combine at block end (partial layout
// identical to previous round: f4 slot 256j+t covers l=1024j+4t).
__global__ __launch_bounds__(256, 2)
void k_main(const float* __restrict__ x, float* __restrict__ g,
            f4* __restrict__ pd4, f4* __restrict__ ps4) {
    __shared__ f4 ldsD[1024], ldsS[1024];    // 32 KB
    const int tid = threadIdx.x;
    const int w = tid >> 6, lane = tid & 63;
    const int b  = blockIdx.x >> 4;
    const int c0 = (blockIdx.x & 15) * 32;

    f4 dA[16], sA[16];
#pragma unroll
    for (int i = 0; i < 16; ++i) { dA[i] = (f4)0.f; sA[i] = (f4)0.f; }

    const f4* base = (const f4*)(x + ((size_t)b * CC + c0 + w * 8) * LL);
    for (int cc = 0; cc < 8; ++cc) {
        const f4* row = base + (size_t)cc * 1024;
        f4 v[16];
#pragma unroll
        for (int i = 0; i < 16; ++i) v[i] = __builtin_nontemporal_load(&row[i * 64 + lane]);
        float s = 0.f;
#pragma unroll
        for (int i = 0; i < 16; ++i) s += (v[i][0] + v[i][1]) + (v[i][2] + v[i][3]);
#pragma unroll
        for (int off = 32; off; off >>= 1) s += __shfl_down(s, off, 64);
        s = __shfl(s, 0, 64);                // broadcast
        const float gv = s * (1.0f / LL);
        if (lane == 0) g[b * CC + c0 + w * 8 + cc] = gv;
#pragma unroll
        for (int i = 0; i < 16; ++i) {
#pragma unroll
            for (int k = 0; k < 4; ++k) {
                dA[i][k] = fmaf(v[i][k], gv, dA[i][k]);
                sA[i][k] = fmaf(v[i][k], v[i][k], sA[i][k]);
            }
        }
    }
    // 4-step wave combine (ascending w keeps c-summation order == previous rounds)
    for (int ww = 0; ww < 4; ++ww) {
        if (w == ww) {
#pragma unroll
            for (int i = 0; i < 16; ++i) {
                const int idx = i * 64 + lane;
                if (ww == 0) { ldsD[idx] = dA[i];  ldsS[idx] = sA[i]; }
                else         { ldsD[idx] += dA[i]; ldsS[idx] += sA[i]; }
            }
        }
        __syncthreads();
    }
#pragma unroll
    for (int j = 0; j < 4; ++j) {
        pd4[(size_t)blockIdx.x * 1024 + j * 256 + tid] = ldsD[j * 256 + tid];
        ps4[(size_t)blockIdx.x * 1024 + j * 256 + tid] = ldsS[j * 256 + tid];
    }
}

// ---------------- reduce: fold chunk partials -> cos + min/max partials ----
// 256 blocks (b x 8) x 128 threads; thread owns one l-quad (float4).
__global__ void k_reduce(const float* __restrict__ g,
                         const f4* __restrict__ pd4, const f4* __restrict__ ps4,
                         f4* __restrict__ cosv4,
                         float* __restrict__ pmin, float* __restrict__ pmax) {
    const int tid = threadIdx.x;            // 0..127
    const int w = tid >> 6, lane = tid & 63;
    const int b = blockIdx.x >> 3;
    const int q = blockIdx.x & 7;
    const int s = q * 128 + tid;            // quad slot in [0,1024)

    // gn = sqrt(sum_c g^2) (block-redundant, L2-hot)
    f4 g4 = ((const f4*)g)[b * 128 + tid];
    float sq = fmaf(g4[0], g4[0], fmaf(g4[1], g4[1], fmaf(g4[2], g4[2], g4[3] * g4[3])));
#pragma unroll
    for (int off = 32; off; off >>= 1) sq += __shfl_down(sq, off, 64);
    __shared__ float sw[2];
    if (lane == 0) sw[w] = sq;
    __syncthreads();
    const float gn = sqrtf(sw[0] + sw[1]);

    f4 pdv = (f4)0.f, psv = (f4)0.f;
#pragma unroll
    for (int ch = 0; ch < 16; ++ch) {
        pdv += pd4[(((size_t)b * 16 + ch) << 10) + s];
        psv += ps4[(((size_t)b * 16 + ch) << 10) + s];
    }
    f4 cs;
#pragma unroll
    for (int k = 0; k < 4; ++k)
        cs[k] = pdv[k] / fmaxf(sqrtf(psv[k]) * gn, EPSF);
    cosv4[(size_t)b * 1024 + s] = cs;

    float mn = fminf(fminf(cs[0], cs[1]), fminf(cs[2], cs[3]));
    float mx = fmaxf(fmaxf(cs[0], cs[1]), fmaxf(cs[2], cs[3]));
#pragma unroll
    for (int off = 32; off; off >>= 1) {
        mn = fminf(mn, __shfl_down(mn, off, 64));
        mx = fmaxf(mx, __shfl_down(mx, off, 64));
    }
    __shared__ float smn[2], smx[2];
    if (lane == 0) { smn[w] = mn; smx[w] = mx; }
    __syncthreads();
    if (tid == 0) {
        pmin[blockIdx.x] = fminf(smn[0], smn[1]);
        pmax[blockIdx.x] = fmaxf(smx[0], smx[1]);
    }
}

// ---------------- histogram per b, normalize, broadcast ----------------
__global__ void k_hist(const float* __restrict__ cosv,
                       const float* __restrict__ pmin, const float* __restrict__ pmax,
                       float* __restrict__ out) {
    const int b = blockIdx.x;
    const int wave = threadIdx.x >> 6, lane = threadIdx.x & 63;

    float mn = pmin[threadIdx.x];           // 256 partials, one per thread
    float mx = pmax[threadIdx.x];
#pragma unroll
    for (int off = 32; off; off >>= 1) {
        mn = fminf(mn, __shfl_down(mn, off, 64));
        mx = fmaxf(mx, __shfl_down(mx, off, 64));
    }
    __shared__ float smn[4], smx[4];
    if (lane == 0) { smn[wave] = mn; smx[wave] = mx; }
    __syncthreads();
    mn = fminf(fminf(smn[0], smn[1]), fminf(smn[2], smn[3]));
    mx = fmaxf(fmaxf(smx[0], smx[1]), fmaxf(smx[2], smx[3]));
    const float range = mx - mn;

    float bins[NB];
#pragma unroll
    for (int n = 0; n < NB; ++n) bins[n] = 0.f;

    const float* cb = cosv + (b << 12);
    for (int l = threadIdx.x; l < LL; l += 256) {
        float s = cb[l];
#pragma unroll
        for (int n = 0; n < NB; ++n) {
            float lev = mn + ((float)n * range) / 15.0f;   // match ref order of ops
            float d = fabsf(s - lev);
            bins[n] += (d < 0.03125f) ? (1.0f - d) : 0.f;
        }
    }
#pragma unroll
    for (int n = 0; n < NB; ++n) {
#pragma unroll
        for (int off = 32; off; off >>= 1) bins[n] += __shfl_down(bins[n], off, 64);
    }
    __shared__ float sb[4][NB];
    if (lane == 0) {
#pragma unroll
        for (int n = 0; n < NB; ++n) sb[wave][n] = bins[n];
    }
    __syncthreads();
    __shared__ float colsum[NB];
    if (threadIdx.x < NB) {
        const int n = threadIdx.x;
        colsum[n] = sb[0][n] + sb[1][n] + sb[2][n] + sb[3][n];
    }
    __syncthreads();
    float total = 0.f;
#pragma unroll
    for (int n = 0; n < NB; ++n) total += colsum[n];
    {
        const int i0 = threadIdx.x;
        out[b * (NB * 32) + i0]       = colsum[i0 >> 5] / total;
        out[b * (NB * 32) + i0 + 256] = colsum[(i0 + 256) >> 5] / total;
    }
}

extern "C" void kernel_launch(void* const* d_in, const int* in_sizes, int n_in,
                              void* d_out, int out_size, void* d_ws, size_t ws_size,
                              hipStream_t stream) {
    const float* x = (const float*)d_in[0];
    float* out = (float*)d_out;
    float* ws  = (float*)d_ws;

    float* g    = ws;                      // 16384 floats
    float* cosv = ws + 16384;              // 131072 floats
    float* pmin = ws + 16384 + 131072;     // 256
    float* pmax = pmin + 256;              // 256
    f4*    pd4  = (f4*)(pmax + 256);       // 512 blocks * 1024 f4 = 2M floats
    f4*    ps4  = pd4 + 524288;            // 2M floats

    k_main<<<512, 256, 0, stream>>>(x, g, pd4, ps4);
    k_reduce<<<256, 128, 0, stream>>>(g, pd4, ps4, (f4*)cosv, pmin, pmax);
    k_hist<<<32, 256, 0, stream>>>(cosv, pmin, pmax, out);
}

// Round 6
// 66.087 us; speedup vs baseline: 1.0516x; 1.0516x over previous
//
#include <hip/hip_runtime.h>

typedef float f4 __attribute__((ext_vector_type(4)));

#define BB 32
#define CC 512
#define LL 4096
#define NB 16
#define EPSF 1e-8f

// ---------------- fused main kernel: barrier-free, ONE read of x ----------
// grid = 32 b x 16 chunks = 512 blocks (2/CU). Wave w owns channels
// c0+8w..c0+8w+7, processes each row fully in registers (plain loads —
// NT loads regressed in R3/R4). Lane holds l = 256i + 4*lane + k.
__global__ __launch_bounds__(256, 2)
void k_main(const float* __restrict__ x, float* __restrict__ g,
            f4* __restrict__ pd4, f4* __restrict__ ps4) {
    __shared__ f4 ldsD[1024], ldsS[1024];    // 32 KB
    const int tid = threadIdx.x;
    const int w = tid >> 6, lane = tid & 63;
    const int b  = blockIdx.x >> 4;
    const int c0 = (blockIdx.x & 15) * 32;

    f4 dA[16], sA[16];
#pragma unroll
    for (int i = 0; i < 16; ++i) { dA[i] = (f4)0.f; sA[i] = (f4)0.f; }

    const f4* base = (const f4*)(x + ((size_t)b * CC + c0 + w * 8) * LL);
    for (int cc = 0; cc < 8; ++cc) {
        const f4* row = base + (size_t)cc * 1024;
        f4 v[16];
#pragma unroll
        for (int i = 0; i < 16; ++i) v[i] = row[i * 64 + lane];
        float s = 0.f;
#pragma unroll
        for (int i = 0; i < 16; ++i) s += (v[i][0] + v[i][1]) + (v[i][2] + v[i][3]);
#pragma unroll
        for (int off = 32; off; off >>= 1) s += __shfl_down(s, off, 64);
        s = __shfl(s, 0, 64);                // broadcast
        const float gv = s * (1.0f / LL);
        if (lane == 0) g[b * CC + c0 + w * 8 + cc] = gv;
#pragma unroll
        for (int i = 0; i < 16; ++i) {
#pragma unroll
            for (int k = 0; k < 4; ++k) {
                dA[i][k] = fmaf(v[i][k], gv, dA[i][k]);
                sA[i][k] = fmaf(v[i][k], v[i][k], sA[i][k]);
            }
        }
    }
    // 4-step wave combine (ascending w keeps c-summation order)
    for (int ww = 0; ww < 4; ++ww) {
        if (w == ww) {
#pragma unroll
            for (int i = 0; i < 16; ++i) {
                const int idx = i * 64 + lane;
                if (ww == 0) { ldsD[idx] = dA[i];  ldsS[idx] = sA[i]; }
                else         { ldsD[idx] += dA[i]; ldsS[idx] += sA[i]; }
            }
        }
        __syncthreads();
    }
#pragma unroll
    for (int j = 0; j < 4; ++j) {
        pd4[(size_t)blockIdx.x * 1024 + j * 256 + tid] = ldsD[j * 256 + tid];
        ps4[(size_t)blockIdx.x * 1024 + j * 256 + tid] = ldsS[j * 256 + tid];
    }
}

// ---------------- reduce: fold chunk partials -> cos + min/max partials ----
// 512 blocks x 256 threads (8 waves/CU). Block owns 64 quads; wave w folds
// chunks 4w..4w+3 (4+4 coalesced f4 loads/lane), LDS combine, wave 0
// finishes cos + min/max. 4x the TLP of the previous version.
__global__ __launch_bounds__(256, 8)
void k_reduce(const float* __restrict__ g,
              const f4* __restrict__ pd4, const f4* __restrict__ ps4,
              f4* __restrict__ cosv4,
              float* __restrict__ pmin, float* __restrict__ pmax) {
    const int tid = threadIdx.x;
    const int w = tid >> 6, lane = tid & 63;
    const int b = blockIdx.x >> 4;
    const int sl = (blockIdx.x & 15) * 64 + lane;   // quad slot within b

    f4 pdv = (f4)0.f, psv = (f4)0.f;
    const size_t cb = (size_t)b * 16;
#pragma unroll
    for (int c = 0; c < 4; ++c) {
        const int ch = 4 * w + c;
        pdv += pd4[((cb + ch) << 10) + sl];
        psv += ps4[((cb + ch) << 10) + sl];
    }
    __shared__ f4 sD[4][64], sS[4][64];
    sD[w][lane] = pdv;
    sS[w][lane] = psv;

    // per-wave redundant gn (L2-hot, overlaps with partial loads)
    const f4* g4p = (const f4*)(g + b * CC);
    f4 ga = g4p[lane], gb2 = g4p[64 + lane];
    float sq = 0.f;
#pragma unroll
    for (int k = 0; k < 4; ++k) sq = fmaf(ga[k], ga[k], fmaf(gb2[k], gb2[k], sq));
#pragma unroll
    for (int off = 32; off; off >>= 1) sq += __shfl_down(sq, off, 64);
    const float gn = sqrtf(__shfl(sq, 0, 64));

    __syncthreads();
    if (tid < 64) {
        f4 d = ((sD[0][lane] + sD[1][lane]) + sD[2][lane]) + sD[3][lane];
        f4 ssum = ((sS[0][lane] + sS[1][lane]) + sS[2][lane]) + sS[3][lane];
        f4 cs;
#pragma unroll
        for (int k = 0; k < 4; ++k)
            cs[k] = d[k] / fmaxf(sqrtf(ssum[k]) * gn, EPSF);
        cosv4[(size_t)b * 1024 + sl] = cs;

        float mn = fminf(fminf(cs[0], cs[1]), fminf(cs[2], cs[3]));
        float mx = fmaxf(fmaxf(cs[0], cs[1]), fmaxf(cs[2], cs[3]));
#pragma unroll
        for (int off = 32; off; off >>= 1) {
            mn = fminf(mn, __shfl_down(mn, off, 64));
            mx = fmaxf(mx, __shfl_down(mx, off, 64));
        }
        if (lane == 0) { pmin[blockIdx.x] = mn; pmax[blockIdx.x] = mx; }
    }
}

// ---------------- histogram per b, normalize, broadcast ----------------
__global__ void k_hist(const float* __restrict__ cosv,
                       const float* __restrict__ pmin, const float* __restrict__ pmax,
                       float* __restrict__ out) {
    const int b = blockIdx.x;
    const int wave = threadIdx.x >> 6, lane = threadIdx.x & 63;

    float mn = fminf(pmin[threadIdx.x], pmin[threadIdx.x + 256]);   // 512 partials
    float mx = fmaxf(pmax[threadIdx.x], pmax[threadIdx.x + 256]);
#pragma unroll
    for (int off = 32; off; off >>= 1) {
        mn = fminf(mn, __shfl_down(mn, off, 64));
        mx = fmaxf(mx, __shfl_down(mx, off, 64));
    }
    __shared__ float smn[4], smx[4];
    if (lane == 0) { smn[wave] = mn; smx[wave] = mx; }
    __syncthreads();
    mn = fminf(fminf(smn[0], smn[1]), fminf(smn[2], smn[3]));
    mx = fmaxf(fmaxf(smx[0], smx[1]), fmaxf(smx[2], smx[3]));
    const float range = mx - mn;

    float bins[NB];
#pragma unroll
    for (int n = 0; n < NB; ++n) bins[n] = 0.f;

    const float* cb = cosv + (b << 12);
    for (int l = threadIdx.x; l < LL; l += 256) {
        float s = cb[l];
#pragma unroll
        for (int n = 0; n < NB; ++n) {
            float lev = mn + ((float)n * range) / 15.0f;   // match ref order of ops
            float d = fabsf(s - lev);
            bins[n] += (d < 0.03125f) ? (1.0f - d) : 0.f;
        }
    }
#pragma unroll
    for (int n = 0; n < NB; ++n) {
#pragma unroll
        for (int off = 32; off; off >>= 1) bins[n] += __shfl_down(bins[n], off, 64);
    }
    __shared__ float sb[4][NB];
    if (lane == 0) {
#pragma unroll
        for (int n = 0; n < NB; ++n) sb[wave][n] = bins[n];
    }
    __syncthreads();
    __shared__ float colsum[NB];
    if (threadIdx.x < NB) {
        const int n = threadIdx.x;
        colsum[n] = sb[0][n] + sb[1][n] + sb[2][n] + sb[3][n];
    }
    __syncthreads();
    float total = 0.f;
#pragma unroll
    for (int n = 0; n < NB; ++n) total += colsum[n];
    {
        const int i0 = threadIdx.x;
        out[b * (NB * 32) + i0]       = colsum[i0 >> 5] / total;
        out[b * (NB * 32) + i0 + 256] = colsum[(i0 + 256) >> 5] / total;
    }
}

extern "C" void kernel_launch(void* const* d_in, const int* in_sizes, int n_in,
                              void* d_out, int out_size, void* d_ws, size_t ws_size,
                              hipStream_t stream) {
    const float* x = (const float*)d_in[0];
    float* out = (float*)d_out;
    float* ws  = (float*)d_ws;

    float* g    = ws;                      // 16384 floats
    float* cosv = ws + 16384;              // 131072 floats
    float* pmin = ws + 16384 + 131072;     // 512
    float* pmax = pmin + 512;              // 512
    f4*    pd4  = (f4*)(pmax + 512);       // 512 blocks * 1024 f4 = 2M floats
    f4*    ps4  = pd4 + 524288;            // 2M floats

    k_main<<<512, 256, 0, stream>>>(x, g, pd4, ps4);
    k_reduce<<<512, 256, 0, stream>>>(g, pd4, ps4, (f4*)cosv, pmin, pmax);
    k_hist<<<32, 256, 0, stream>>>(cosv, pmin, pmax, out);
}